// Round 21
// baseline (109.953 us; speedup 1.0000x reference)
//
#include <hip/hip_runtime.h>
#include <hip/hip_bf16.h>
#include <cstdint>
#include <cstddef>

typedef __bf16 bf16_t;
typedef __bf16 bf16x4 __attribute__((ext_vector_type(4)));
typedef __bf16 bf16x8 __attribute__((ext_vector_type(8)));
typedef float  f32x4  __attribute__((ext_vector_type(4)));
typedef float  f32x16 __attribute__((ext_vector_type(16)));
typedef unsigned int u32;
typedef unsigned int u32x4 __attribute__((ext_vector_type(4)));

#define DIM_   1024
#define HEADS_ 16
#define HD_    64
#define BB_    2
#define NN_    2048
#define MTOT   (BB_*NN_)
static constexpr float SCALE_ = 0.03125f;              // 1/sqrt(1024)
static constexpr float EXPC_  = 0.045084220027780106f; // SCALE * log2(e), folded into q-proj

__device__ __forceinline__ float exp2_hw(float x) {
    float r;
    asm("v_exp_f32 %0, %1" : "=v"(r) : "v"(x));
    return r;
}

// ---------------------------------------------------------------------------
// fp32 -> bf16 bulk convert, all 5 arrays in one launch.
// ---------------------------------------------------------------------------
__global__ __launch_bounds__(256) void cvt_all(
    const float* __restrict__ X,
    const float* __restrict__ W0, const float* __restrict__ W1,
    const float* __restrict__ W2, const float* __restrict__ W3,
    bf16_t* __restrict__ xo,
    bf16_t* __restrict__ o0, bf16_t* __restrict__ o1,
    bf16_t* __restrict__ o2, bf16_t* __restrict__ o3)
{
    const int bid = blockIdx.x;
    const float* src;
    bf16_t* dst;
    int lb;
    if (bid < 2048) { src = X; dst = xo; lb = bid; }
    else {
        const int w = (bid - 2048) >> 9;
        lb = (bid - 2048) & 511;
        src = (w == 0) ? W0 : (w == 1) ? W1 : (w == 2) ? W2 : W3;
        dst = (w == 0) ? o0 : (w == 1) ? o1 : (w == 2) ? o2 : o3;
    }
    const size_t i = ((size_t)lb * 256 + threadIdx.x) * 8;
    f32x4 a = *(const f32x4*)(src + i);
    f32x4 b = *(const f32x4*)(src + i + 4);
    bf16x8 o;
    o[0] = (bf16_t)a.x; o[1] = (bf16_t)a.y; o[2] = (bf16_t)a.z; o[3] = (bf16_t)a.w;
    o[4] = (bf16_t)b.x; o[5] = (bf16_t)b.y; o[6] = (bf16_t)b.z; o[7] = (bf16_t)b.w;
    *(bf16x8*)(dst + i) = o;
}

// ---------------------------------------------------------------------------
__device__ __forceinline__ void gld16(const bf16_t* g, bf16_t* l) {
    __builtin_amdgcn_global_load_lds(
        (const __attribute__((address_space(1))) unsigned int*)g,
        (__attribute__((address_space(3))) unsigned int*)l, 16, 0, 0);
}

// ---------------------------------------------------------------------------
// Fused QKV GEMM, BK=64 dbuf, fused per-head V^T output, T2 XOR-swizzled LDS.
// (verified round 15)
// ---------------------------------------------------------------------------
__global__ __launch_bounds__(512) void gemm_qkv(
    const bf16_t* __restrict__ A,
    const bf16_t* __restrict__ Wq, const bf16_t* __restrict__ Wk, const bf16_t* __restrict__ Wv,
    const float* __restrict__ bq, const float* __restrict__ bk, const float* __restrict__ bv,
    bf16_t* __restrict__ Cq, bf16_t* __restrict__ Ck, bf16_t* __restrict__ Vt)
{
    __shared__ __align__(16) bf16_t As[2][128 * 64];      // 32KB
    __shared__ __align__(16) bf16_t Bs[2][3 * 64 * 64];   // 48KB

    const int tid  = threadIdx.x;
    const int lane = tid & 63;
    const int w    = tid >> 6;        // 0..7
    const int wr   = w >> 1;          // 0..3: 32-row strip
    const int wc   = w & 1;           // 0..1: 32-col half
    const int bn   = blockIdx.x;      // 0..15 == head h
    const int bm   = blockIdx.y;      // 0..31

    const int l15 = lane & 15;
    const int g   = lane >> 4;
    const int sw  = l15 & 7;           // read-side row XOR key

    const int srow = lane >> 3;                          // 0..7 within chunk
    const int scol = ((lane & 7) ^ srow) * 8;            // pre-swizzled source col

    const bf16_t* aSrc0 = A  + (size_t)(bm * 128 + (w * 2 + 0) * 8 + srow) * DIM_ + scol;
    const bf16_t* aSrc1 = A  + (size_t)(bm * 128 + (w * 2 + 1) * 8 + srow) * DIM_ + scol;
    const bf16_t* qSrc  = Wq + (size_t)(bn * 64 + w * 8 + srow) * DIM_ + scol;
    const bf16_t* kSrc  = Wk + (size_t)(bn * 64 + w * 8 + srow) * DIM_ + scol;
    const bf16_t* vSrc  = Wv + (size_t)(bn * 64 + w * 8 + srow) * DIM_ + scol;

    f32x4 aq[2][2], ak[2][2], av[2][2];
    #pragma unroll
    for (int i = 0; i < 2; i++)
        #pragma unroll
        for (int j = 0; j < 2; j++) {
            aq[i][j] = (f32x4){0.f, 0.f, 0.f, 0.f};
            ak[i][j] = (f32x4){0.f, 0.f, 0.f, 0.f};
            av[i][j] = (f32x4){0.f, 0.f, 0.f, 0.f};
        }

    #define QSTAGE(buf, kb)                                       \
        {                                                         \
            gld16(aSrc0 + (kb), &As[buf][(w * 2 + 0) * 512]);     \
            gld16(aSrc1 + (kb), &As[buf][(w * 2 + 1) * 512]);     \
            gld16(qSrc + (kb), &Bs[buf][w * 512]);                \
            gld16(kSrc + (kb), &Bs[buf][4096 + w * 512]);         \
            gld16(vSrc + (kb), &Bs[buf][8192 + w * 512]);         \
        }

    QSTAGE(0, 0);
    __syncthreads();

    for (int t = 0; t < 16; t++) {
        const int cur = t & 1;
        if (t < 15) QSTAGE(cur ^ 1, (t + 1) * 64);

        #pragma unroll
        for (int kk = 0; kk < 2; kk++) {
            const int swc = ((kk * 4 + g) ^ sw) * 8;   // swizzled col offset
            bf16x8 af[2];
            #pragma unroll
            for (int i = 0; i < 2; i++)
                af[i] = *(const bf16x8*)&As[cur][(wr * 32 + i * 16 + l15) * 64 + swc];
            bf16x8 bqf[2], bkf[2], bvf[2];
            #pragma unroll
            for (int j = 0; j < 2; j++) {
                const int off = (wc * 32 + j * 16 + l15) * 64 + swc;
                bqf[j] = *(const bf16x8*)&Bs[cur][off];
                bkf[j] = *(const bf16x8*)&Bs[cur][4096 + off];
                bvf[j] = *(const bf16x8*)&Bs[cur][8192 + off];
            }
            #pragma unroll
            for (int i = 0; i < 2; i++)
                #pragma unroll
                for (int j = 0; j < 2; j++) {
                    aq[i][j] = __builtin_amdgcn_mfma_f32_16x16x32_bf16(af[i], bqf[j], aq[i][j], 0, 0, 0);
                    ak[i][j] = __builtin_amdgcn_mfma_f32_16x16x32_bf16(af[i], bkf[j], ak[i][j], 0, 0, 0);
                    av[i][j] = __builtin_amdgcn_mfma_f32_16x16x32_bf16(af[i], bvf[j], av[i][j], 0, 0, 0);
                }
        }

        __syncthreads();
    }
    #undef QSTAGE

    // epilogue: q,k direct; v -> LDS transpose -> coalesced V^T write
    bf16_t* Ts = (bf16_t*)As;
    const int r4 = g * 4;
    #pragma unroll
    for (int j = 0; j < 2; j++) {
        const int lc = wc * 32 + j * 16 + l15;
        const int gc = bn * 64 + lc;
        const float vq = bq[gc], vk = bk[gc], vv = bv[gc];
        #pragma unroll
        for (int i = 0; i < 2; i++) {
            #pragma unroll
            for (int r = 0; r < 4; r++) {
                const int lm = wr * 32 + i * 16 + r4 + r;
                const size_t gr = (size_t)(bm * 128 + lm) * DIM_ + gc;
                Cq[gr] = (bf16_t)((aq[i][j][r] + vq) * EXPC_);
                Ck[gr] = (bf16_t)(ak[i][j][r] + vk);
                Ts[lc * 136 + lm] = (bf16_t)(av[i][j][r] + vv);
            }
        }
    }
    __syncthreads();
    {
        const int b  = bm >> 4;
        const int m0 = (bm & 15) * 128;
        const int d  = tid >> 3;
        const int c  = (tid & 7) * 16;
        bf16x8 v0 = *(const bf16x8*)&Ts[d * 136 + c];
        bf16x8 v1 = *(const bf16x8*)&Ts[d * 136 + c + 8];
        bf16_t* dst = Vt + ((size_t)(b * HEADS_ + bn) * HD_ + d) * NN_ + m0 + c;
        *(bf16x8*)dst       = v0;
        *(bf16x8*)(dst + 8) = v1;
    }
}

// ---------------------------------------------------------------------------
// O-proj GEMM, 2-phase dbuf + T2 XOR-swizzled LDS (verified round 15).
// ---------------------------------------------------------------------------
__global__ __launch_bounds__(512) void gemm_o(
    const bf16_t* __restrict__ A, const bf16_t* __restrict__ Wo,
    const float* __restrict__ bo, float* __restrict__ C)
{
    __shared__ __align__(16) bf16_t As[2][64 * 64];
    __shared__ __align__(16) bf16_t Bs[2][128 * 64];

    const int tid  = threadIdx.x;
    const int lane = tid & 63;
    const int w    = tid >> 6;
    const int wr   = w & 1;
    const int wc   = w >> 1;
    const int bn   = blockIdx.x;
    const int bm   = blockIdx.y;

    const int l15 = lane & 15;
    const int g   = lane >> 4;
    const int sw  = l15 & 7;

    const int srow = lane >> 3;
    const int scol = ((lane & 7) ^ srow) * 8;

    const bf16_t* aSrc  = A  + (size_t)(bm * 64 + w * 8 + srow) * DIM_ + scol;
    const bf16_t* b0Src = Wo + (size_t)(bn * 128 + (w * 2 + 0) * 8 + srow) * DIM_ + scol;
    const bf16_t* b1Src = Wo + (size_t)(bn * 128 + (w * 2 + 1) * 8 + srow) * DIM_ + scol;

    f32x4 acc[2][2];
    #pragma unroll
    for (int i = 0; i < 2; i++)
        #pragma unroll
        for (int j = 0; j < 2; j++)
            acc[i][j] = (f32x4){0.f, 0.f, 0.f, 0.f};

    #define OSTAGE(buf, kb)                                          \
        {                                                            \
            gld16(aSrc + (kb), &As[buf][w * 512]);                   \
            gld16(b0Src + (kb), &Bs[buf][(w * 2 + 0) * 512]);        \
            gld16(b1Src + (kb), &Bs[buf][(w * 2 + 1) * 512]);        \
        }

    OSTAGE(0, 0);
    __syncthreads();

    for (int t = 0; t < 16; t++) {
        const int cur = t & 1;
        if (t < 15) OSTAGE(cur ^ 1, (t + 1) * 64);

        #pragma unroll
        for (int kk = 0; kk < 2; kk++) {
            const int swc = ((kk * 4 + g) ^ sw) * 8;
            bf16x8 af[2], bf[2];
            #pragma unroll
            for (int i = 0; i < 2; i++)
                af[i] = *(const bf16x8*)&As[cur][(wr * 32 + i * 16 + l15) * 64 + swc];
            #pragma unroll
            for (int j = 0; j < 2; j++)
                bf[j] = *(const bf16x8*)&Bs[cur][(wc * 32 + j * 16 + l15) * 64 + swc];
            #pragma unroll
            for (int i = 0; i < 2; i++)
                #pragma unroll
                for (int j = 0; j < 2; j++)
                    acc[i][j] = __builtin_amdgcn_mfma_f32_16x16x32_bf16(af[i], bf[j], acc[i][j], 0, 0, 0);
        }

        __syncthreads();
    }
    #undef OSTAGE

    const int r4 = g * 4;
    #pragma unroll
    for (int j = 0; j < 2; j++) {
        const int gc = bn * 128 + wc * 32 + j * 16 + l15;
        const float bv = bo[gc];
        #pragma unroll
        for (int i = 0; i < 2; i++) {
            #pragma unroll
            for (int r = 0; r < 4; r++) {
                const size_t gr = (size_t)(bm * 64 + wr * 32 + i * 16 + r4 + r) * DIM_ + gc;
                C[gr] = acc[i][j][r] + bv;
            }
        }
    }
}

// ---------------------------------------------------------------------------
// MFMA attention v12b: split-m flash-decoding, fixed LDS aliasing.
// Single S[4][64*72] allocation: S[0..1]=K dbuf, S[2..3]=V dbuf; the
// epilogue scratch (float*)S legally spans all 9216 floats (r10-verified
// merge scheme).  1024 blocks, KVBLK=64 dbuf, __launch_bounds__(512,4)
// (empirically VGPR cap 64 -> no spill; 4 blocks/CU by LDS 36.9KB).
// ---------------------------------------------------------------------------
__device__ __forceinline__ u32 cvtpk_bf16(float lo, float hi) {
    u32 d;
    asm volatile("v_cvt_pk_bf16_f32 %0, %1, %2" : "=v"(d) : "v"(lo), "v"(hi));
    return d;
}

__global__ __launch_bounds__(512, 4) void attn_mfma12(
    const bf16_t* __restrict__ Qa,   // kb (attention-query rows n)
    const bf16_t* __restrict__ Ka,   // qb (attention-key rows m, pre-scaled by EXPC_)
    const bf16_t* __restrict__ Vtg,  // V^T per head [bh][d][m]
    bf16_t* __restrict__ Pbase,      // partials: Pbase + mh*SEG
    float* __restrict__ Lbuf)        // L partials: Lbuf + mh*65536 + bh*2048 + n
{
    __shared__ __align__(16) bf16_t S[4][64 * 72];   // 36.9 KB total

    const int tid  = threadIdx.x;
    const int lane = tid & 63;
    const int w    = tid >> 6;       // 0..7
    const int l31  = lane & 31;
    const int h5   = lane >> 5;

    const int nw = (w & 3) * 32;     // wave's n-offset in block
    const int mo = (w >> 2) * 32;    // wave's m-half within each 64-m tile

    // swizzle: 1024 blocks; mh pairs adjacent (same XCD)
    const int wg  = blockIdx.x;
    const int id  = (wg & 7) * 128 + (wg >> 3);
    const int mh  = id & 1;
    const int id2 = id >> 1;
    const int bh  = id2 >> 4;        // 0..31
    const int nt  = id2 & 15;        // 0..15
    const int b   = bh >> 4, h = bh & 15;
    const int n0  = nt * 128;
    const int mbase = mh * (NN_ / 2);

    const size_t base = (size_t)b * NN_ * DIM_ + h * HD_;

    const bf16_t* qrow = Qa + base + (size_t)(n0 + nw + l31) * DIM_ + h5 * 8;
    bf16x8 qf[4];
    #pragma unroll
    for (int ks = 0; ks < 4; ks++)
        qf[ks] = *(const bf16x8*)(qrow + ks * 16);

    f32x16 oa0 = {}, oa1 = {};
    float Lp = 0.f;

    const bf16_t* vrow   = Vtg + (size_t)bh * HD_ * NN_;
    const bf16_t* kgbase = Ka + base;

    const int sr3 = tid >> 3;          // 0..63
    const int sc3 = (tid & 7) * 8;     // 0..56

    bf16x8 kA0, vA0;

    #define ISSUE(m0v)                                                              \
        {                                                                           \
            kA0 = *(const bf16x8*)(kgbase + (size_t)((m0v) + sr3) * DIM_ + sc3);    \
            vA0 = *(const bf16x8*)(vrow + (size_t)sr3 * NN_ + (m0v) + sc3);         \
        }
    #define COMMIT(buf)                                                             \
        {                                                                           \
            *(bf16x8*)(S[buf] + sr3 * 72 + sc3)     = kA0;                          \
            *(bf16x8*)(S[2 + buf] + sr3 * 72 + sc3) = vA0;                          \
        }

    ISSUE(mbase);
    COMMIT(0);
    __syncthreads();

    for (int t = 0; t < 16; t++) {
        const int cur = t & 1;
        if (t < 15) ISSUE(mbase + (t + 1) * 64);

        const bf16_t* KtC = S[cur];
        const bf16_t* VsC = S[2 + cur];

        // S^T for this wave's 32-m slice: lane holds 16 P-vals for n = nw+l31
        f32x16 sa = {};
        __builtin_amdgcn_s_setprio(1);
        #pragma unroll
        for (int ks = 0; ks < 4; ks++) {
            bf16x8 kf = *(const bf16x8*)&KtC[(mo + l31) * 72 + ks * 16 + h5 * 8];
            sa = __builtin_amdgcn_mfma_f32_32x32x16_bf16(kf, qf[ks], sa, 0, 0, 0);
        }
        __builtin_amdgcn_s_setprio(0);

        // P = exp2(S^T); scalar per-lane L
        float p[16];
        #pragma unroll
        for (int r = 0; r < 16; r++) p[r] = exp2_hw(sa[r]);
        {
            float s0 = (p[0] + p[1]) + (p[2] + p[3]);
            float s1 = (p[4] + p[5]) + (p[6] + p[7]);
            float s2 = (p[8] + p[9]) + (p[10] + p[11]);
            float s3 = (p[12] + p[13]) + (p[14] + p[15]);
            Lp += (s0 + s1) + (s2 + s3);
        }

        // PV A-fragments in-register
        bf16x8 pf[2];
        #pragma unroll
        for (int mb = 0; mb < 2; mb++) {
            const int rb = mb * 8;
            u32 x0 = cvtpk_bf16(p[rb + 0], p[rb + 1]);
            u32 x1 = cvtpk_bf16(p[rb + 2], p[rb + 3]);
            u32 y0 = cvtpk_bf16(p[rb + 4], p[rb + 5]);
            u32 y1 = cvtpk_bf16(p[rb + 6], p[rb + 7]);
            asm volatile("v_permlane32_swap_b32 %0, %1" : "+v"(x0), "+v"(y0));
            asm volatile("v_permlane32_swap_b32 %0, %1" : "+v"(x1), "+v"(y1));
            u32x4 tt; tt.x = x0; tt.y = x1; tt.z = y0; tt.w = y1;
            pf[mb] = __builtin_bit_cast(bf16x8, tt);
        }

        // O += P·V over this wave's 32-m slice
        __builtin_amdgcn_s_setprio(1);
        #pragma unroll
        for (int ms = 0; ms < 2; ms++) {
            bf16x8 vf0 = *(const bf16x8*)&VsC[l31 * 72 + mo + ms * 16 + h5 * 8];
            bf16x8 vf1 = *(const bf16x8*)&VsC[(32 + l31) * 72 + mo + ms * 16 + h5 * 8];
            oa0 = __builtin_amdgcn_mfma_f32_32x32x16_bf16(pf[ms], vf0, oa0, 0, 0, 0);
            oa1 = __builtin_amdgcn_mfma_f32_32x32x16_bf16(pf[ms], vf1, oa1, 0, 0, 0);
        }
        __builtin_amdgcn_s_setprio(0);

        __syncthreads();
        if (t < 15) {
            COMMIT(cur ^ 1);
            __syncthreads();
        }
    }
    #undef ISSUE
    #undef COMMIT

    // lane + h5-partner cover the wave's full slice per n
    Lp += __shfl_xor(Lp, 32);

    // merge m-half partials (wave w+4 -> wave w), r10-verified 2-round scheme.
    // slot s: 2112 floats = oa0 1024 | oa1 1024 | L 64.  (float*)S = 9216
    // floats; max used = 3*2112 = 6336 -> in bounds.
    float* scratch = (float*)S;
    {
        if (w >= 4 && w < 7) {
            float* buf = scratch + (w - 4) * 2112;
            #pragma unroll
            for (int reg = 0; reg < 16; reg++) {
                buf[reg * 64 + lane]        = oa0[reg];
                buf[1024 + reg * 64 + lane] = oa1[reg];
            }
            buf[2048 + lane] = Lp;
        }
        __syncthreads();
        if (w < 3) {
            const float* buf = scratch + w * 2112;
            #pragma unroll
            for (int reg = 0; reg < 16; reg++) {
                oa0[reg] += buf[reg * 64 + lane];
                oa1[reg] += buf[1024 + reg * 64 + lane];
            }
            Lp += buf[2048 + lane];
        }
        __syncthreads();
        if (w == 7) {
            float* buf = scratch;
            #pragma unroll
            for (int reg = 0; reg < 16; reg++) {
                buf[reg * 64 + lane]        = oa0[reg];
                buf[1024 + reg * 64 + lane] = oa1[reg];
            }
            buf[2048 + lane] = Lp;
        }
        __syncthreads();
        if (w == 3) {
            const float* buf = scratch;
            #pragma unroll
            for (int reg = 0; reg < 16; reg++) {
                oa0[reg] += buf[reg * 64 + lane];
                oa1[reg] += buf[1024 + reg * 64 + lane];
            }
            Lp += buf[2048 + lane];
        }
    }

    // write partials (unnormalized) + L
    if (w < 4) {
        bf16_t* Pp = Pbase + (size_t)mh * ((size_t)MTOT * DIM_);
        if (h5 == 0)
            Lbuf[mh * 65536 + bh * 2048 + n0 + nw + l31] = Lp;
        #pragma unroll
        for (int reg = 0; reg < 16; reg++) {
            const int nr = (reg & 3) + 8 * (reg >> 2) + 4 * h5;
            const size_t rowoff = base + (size_t)(n0 + nw + nr) * DIM_;
            Pp[rowoff + l31]      = (bf16_t)oa0[reg];
            Pp[rowoff + 32 + l31] = (bf16_t)oa1[reg];
        }
    }
}

// ---------------------------------------------------------------------------
// merge: out = (P0 + P1) / (L0 + L1), elementwise over (b, n, h*64+d).
// ---------------------------------------------------------------------------
__global__ __launch_bounds__(256) void merge_o(
    const bf16_t* __restrict__ P0, const bf16_t* __restrict__ P1,
    const float* __restrict__ L0, const float* __restrict__ L1,
    bf16_t* __restrict__ out)
{
    const size_t i = ((size_t)blockIdx.x * 256 + threadIdx.x) * 8;
    const int col = (int)(i & 1023);
    const int row = (int)(i >> 10);       // b*2048 + n
    const int n   = row & 2047;
    const int b   = row >> 11;
    const int bh  = b * HEADS_ + (col >> 6);
    const float L = L0[bh * 2048 + n] + L1[bh * 2048 + n];
    const float inv = 1.f / L;
    bf16x8 a = *(const bf16x8*)(P0 + i);
    bf16x8 c = *(const bf16x8*)(P1 + i);
    bf16x8 o;
    #pragma unroll
    for (int j = 0; j < 8; j++)
        o[j] = (bf16_t)(((float)a[j] + (float)c[j]) * inv);
    *(bf16x8*)(out + i) = o;
}

// ---------------------------------------------------------------------------
extern "C" void kernel_launch(void* const* d_in, const int* in_sizes, int n_in,
                              void* d_out, int out_size, void* d_ws, size_t ws_size,
                              hipStream_t stream)
{
    const float* x  = (const float*)d_in[0];
    const float* Wq = (const float*)d_in[1];
    const float* bq = (const float*)d_in[2];
    const float* Wk = (const float*)d_in[3];
    const float* bk = (const float*)d_in[4];
    const float* Wv = (const float*)d_in[5];
    const float* bv = (const float*)d_in[6];
    const float* Wo = (const float*)d_in[7];
    const float* bo = (const float*)d_in[8];
    float* out = (float*)d_out;

    const size_t SEG = (size_t)MTOT * DIM_;   // 4M elems = 8MB bf16
    bf16_t* xb = (bf16_t*)d_ws;
    bf16_t* qb = xb + SEG;
    bf16_t* kb = qb + SEG;
    bf16_t* vt = kb + SEG;   // V^T written directly by gemm_qkv
    bf16_t* ab = xb;         // xb dead after QKV gemm -> merged attn output

    // bf16 weights in [32MB, 40MB); wqb dead after QKV -> L partial buffer
    bf16_t* wqb = vt + SEG;
    bf16_t* wkb = wqb + (size_t)DIM_ * DIM_;
    bf16_t* wvb = wkb + (size_t)DIM_ * DIM_;
    bf16_t* wob = wvb + (size_t)DIM_ * DIM_;

    // attention partials: d_out as scratch (2 x 8MB bf16), L in dead wqb
    bf16_t* Pbase = (bf16_t*)d_out;
    float*  Lbuf  = (float*)wqb;

    cvt_all<<<dim3(4096), 256, 0, stream>>>(x, Wq, Wk, Wv, Wo, xb, wqb, wkb, wvb, wob);

    gemm_qkv<<<dim3(16, 32), 512, 0, stream>>>(
        xb, wqb, wkb, wvb, bq, bk, bv, qb, kb, vt);

    attn_mfma12<<<dim3(1024), 512, 0, stream>>>(kb, qb, vt, Pbase, Lbuf);

    merge_o<<<dim3(2048), 256, 0, stream>>>(
        Pbase, Pbase + SEG, Lbuf, Lbuf + 65536, ab);

    gemm_o<<<dim3(8, 64), 512, 0, stream>>>(ab, wob, bo, out);
}

// Round 22
// 101.959 us; speedup vs baseline: 1.0784x; 1.0784x over previous
//
#include <hip/hip_runtime.h>
#include <hip/hip_bf16.h>
#include <cstdint>
#include <cstddef>

typedef __bf16 bf16_t;
typedef __bf16 bf16x4 __attribute__((ext_vector_type(4)));
typedef __bf16 bf16x8 __attribute__((ext_vector_type(8)));
typedef float  f32x4  __attribute__((ext_vector_type(4)));
typedef float  f32x16 __attribute__((ext_vector_type(16)));
typedef unsigned int u32;
typedef unsigned int u32x4 __attribute__((ext_vector_type(4)));

#define DIM_   1024
#define HEADS_ 16
#define HD_    64
#define BB_    2
#define NN_    2048
#define MTOT   (BB_*NN_)
static constexpr float SCALE_ = 0.03125f;              // 1/sqrt(1024)
static constexpr float EXPC_  = 0.045084220027780106f; // SCALE * log2(e), folded into q-proj

__device__ __forceinline__ float exp2_hw(float x) {
    float r;
    asm("v_exp_f32 %0, %1" : "=v"(r) : "v"(x));
    return r;
}

// ---------------------------------------------------------------------------
// fp32 -> bf16 bulk convert, all 5 arrays in one launch.
// ---------------------------------------------------------------------------
__global__ __launch_bounds__(256) void cvt_all(
    const float* __restrict__ X,
    const float* __restrict__ W0, const float* __restrict__ W1,
    const float* __restrict__ W2, const float* __restrict__ W3,
    bf16_t* __restrict__ xo,
    bf16_t* __restrict__ o0, bf16_t* __restrict__ o1,
    bf16_t* __restrict__ o2, bf16_t* __restrict__ o3)
{
    const int bid = blockIdx.x;
    const float* src;
    bf16_t* dst;
    int lb;
    if (bid < 2048) { src = X; dst = xo; lb = bid; }
    else {
        const int w = (bid - 2048) >> 9;
        lb = (bid - 2048) & 511;
        src = (w == 0) ? W0 : (w == 1) ? W1 : (w == 2) ? W2 : W3;
        dst = (w == 0) ? o0 : (w == 1) ? o1 : (w == 2) ? o2 : o3;
    }
    const size_t i = ((size_t)lb * 256 + threadIdx.x) * 8;
    f32x4 a = *(const f32x4*)(src + i);
    f32x4 b = *(const f32x4*)(src + i + 4);
    bf16x8 o;
    o[0] = (bf16_t)a.x; o[1] = (bf16_t)a.y; o[2] = (bf16_t)a.z; o[3] = (bf16_t)a.w;
    o[4] = (bf16_t)b.x; o[5] = (bf16_t)b.y; o[6] = (bf16_t)b.z; o[7] = (bf16_t)b.w;
    *(bf16x8*)(dst + i) = o;
}

// ---------------------------------------------------------------------------
__device__ __forceinline__ void gld16(const bf16_t* g, bf16_t* l) {
    __builtin_amdgcn_global_load_lds(
        (const __attribute__((address_space(1))) unsigned int*)g,
        (__attribute__((address_space(3))) unsigned int*)l, 16, 0, 0);
}

// ---------------------------------------------------------------------------
// Fused QKV GEMM, BK=64 dbuf, fused per-head V^T output, T2 XOR-swizzled LDS.
// (verified round 15/19)
// ---------------------------------------------------------------------------
__global__ __launch_bounds__(512) void gemm_qkv(
    const bf16_t* __restrict__ A,
    const bf16_t* __restrict__ Wq, const bf16_t* __restrict__ Wk, const bf16_t* __restrict__ Wv,
    const float* __restrict__ bq, const float* __restrict__ bk, const float* __restrict__ bv,
    bf16_t* __restrict__ Cq, bf16_t* __restrict__ Ck, bf16_t* __restrict__ Vt)
{
    __shared__ __align__(16) bf16_t As[2][128 * 64];      // 32KB
    __shared__ __align__(16) bf16_t Bs[2][3 * 64 * 64];   // 48KB

    const int tid  = threadIdx.x;
    const int lane = tid & 63;
    const int w    = tid >> 6;        // 0..7
    const int wr   = w >> 1;          // 0..3: 32-row strip
    const int wc   = w & 1;           // 0..1: 32-col half
    const int bn   = blockIdx.x;      // 0..15 == head h
    const int bm   = blockIdx.y;      // 0..31

    const int l15 = lane & 15;
    const int g   = lane >> 4;
    const int sw  = l15 & 7;           // read-side row XOR key

    const int srow = lane >> 3;                          // 0..7 within chunk
    const int scol = ((lane & 7) ^ srow) * 8;            // pre-swizzled source col

    const bf16_t* aSrc0 = A  + (size_t)(bm * 128 + (w * 2 + 0) * 8 + srow) * DIM_ + scol;
    const bf16_t* aSrc1 = A  + (size_t)(bm * 128 + (w * 2 + 1) * 8 + srow) * DIM_ + scol;
    const bf16_t* qSrc  = Wq + (size_t)(bn * 64 + w * 8 + srow) * DIM_ + scol;
    const bf16_t* kSrc  = Wk + (size_t)(bn * 64 + w * 8 + srow) * DIM_ + scol;
    const bf16_t* vSrc  = Wv + (size_t)(bn * 64 + w * 8 + srow) * DIM_ + scol;

    f32x4 aq[2][2], ak[2][2], av[2][2];
    #pragma unroll
    for (int i = 0; i < 2; i++)
        #pragma unroll
        for (int j = 0; j < 2; j++) {
            aq[i][j] = (f32x4){0.f, 0.f, 0.f, 0.f};
            ak[i][j] = (f32x4){0.f, 0.f, 0.f, 0.f};
            av[i][j] = (f32x4){0.f, 0.f, 0.f, 0.f};
        }

    #define QSTAGE(buf, kb)                                       \
        {                                                         \
            gld16(aSrc0 + (kb), &As[buf][(w * 2 + 0) * 512]);     \
            gld16(aSrc1 + (kb), &As[buf][(w * 2 + 1) * 512]);     \
            gld16(qSrc + (kb), &Bs[buf][w * 512]);                \
            gld16(kSrc + (kb), &Bs[buf][4096 + w * 512]);         \
            gld16(vSrc + (kb), &Bs[buf][8192 + w * 512]);         \
        }

    QSTAGE(0, 0);
    __syncthreads();

    for (int t = 0; t < 16; t++) {
        const int cur = t & 1;
        if (t < 15) QSTAGE(cur ^ 1, (t + 1) * 64);

        #pragma unroll
        for (int kk = 0; kk < 2; kk++) {
            const int swc = ((kk * 4 + g) ^ sw) * 8;   // swizzled col offset
            bf16x8 af[2];
            #pragma unroll
            for (int i = 0; i < 2; i++)
                af[i] = *(const bf16x8*)&As[cur][(wr * 32 + i * 16 + l15) * 64 + swc];
            bf16x8 bqf[2], bkf[2], bvf[2];
            #pragma unroll
            for (int j = 0; j < 2; j++) {
                const int off = (wc * 32 + j * 16 + l15) * 64 + swc;
                bqf[j] = *(const bf16x8*)&Bs[cur][off];
                bkf[j] = *(const bf16x8*)&Bs[cur][4096 + off];
                bvf[j] = *(const bf16x8*)&Bs[cur][8192 + off];
            }
            #pragma unroll
            for (int i = 0; i < 2; i++)
                #pragma unroll
                for (int j = 0; j < 2; j++) {
                    aq[i][j] = __builtin_amdgcn_mfma_f32_16x16x32_bf16(af[i], bqf[j], aq[i][j], 0, 0, 0);
                    ak[i][j] = __builtin_amdgcn_mfma_f32_16x16x32_bf16(af[i], bkf[j], ak[i][j], 0, 0, 0);
                    av[i][j] = __builtin_amdgcn_mfma_f32_16x16x32_bf16(af[i], bvf[j], av[i][j], 0, 0, 0);
                }
        }

        __syncthreads();
    }
    #undef QSTAGE

    // epilogue: q,k direct; v -> LDS transpose -> coalesced V^T write
    bf16_t* Ts = (bf16_t*)As;
    const int r4 = g * 4;
    #pragma unroll
    for (int j = 0; j < 2; j++) {
        const int lc = wc * 32 + j * 16 + l15;
        const int gc = bn * 64 + lc;
        const float vq = bq[gc], vk = bk[gc], vv = bv[gc];
        #pragma unroll
        for (int i = 0; i < 2; i++) {
            #pragma unroll
            for (int r = 0; r < 4; r++) {
                const int lm = wr * 32 + i * 16 + r4 + r;
                const size_t gr = (size_t)(bm * 128 + lm) * DIM_ + gc;
                Cq[gr] = (bf16_t)((aq[i][j][r] + vq) * EXPC_);
                Ck[gr] = (bf16_t)(ak[i][j][r] + vk);
                Ts[lc * 136 + lm] = (bf16_t)(av[i][j][r] + vv);
            }
        }
    }
    __syncthreads();
    {
        const int b  = bm >> 4;
        const int m0 = (bm & 15) * 128;
        const int d  = tid >> 3;
        const int c  = (tid & 7) * 16;
        bf16x8 v0 = *(const bf16x8*)&Ts[d * 136 + c];
        bf16x8 v1 = *(const bf16x8*)&Ts[d * 136 + c + 8];
        bf16_t* dst = Vt + ((size_t)(b * HEADS_ + bn) * HD_ + d) * NN_ + m0 + c;
        *(bf16x8*)dst       = v0;
        *(bf16x8*)(dst + 8) = v1;
    }
}

// ---------------------------------------------------------------------------
// O-proj GEMM, 2-phase dbuf + T2 XOR-swizzled LDS (verified round 15/19).
// ---------------------------------------------------------------------------
__global__ __launch_bounds__(512) void gemm_o(
    const bf16_t* __restrict__ A, const bf16_t* __restrict__ Wo,
    const float* __restrict__ bo, float* __restrict__ C)
{
    __shared__ __align__(16) bf16_t As[2][64 * 64];
    __shared__ __align__(16) bf16_t Bs[2][128 * 64];

    const int tid  = threadIdx.x;
    const int lane = tid & 63;
    const int w    = tid >> 6;
    const int wr   = w & 1;
    const int wc   = w >> 1;
    const int bn   = blockIdx.x;
    const int bm   = blockIdx.y;

    const int l15 = lane & 15;
    const int g   = lane >> 4;
    const int sw  = l15 & 7;

    const int srow = lane >> 3;
    const int scol = ((lane & 7) ^ srow) * 8;

    const bf16_t* aSrc  = A  + (size_t)(bm * 64 + w * 8 + srow) * DIM_ + scol;
    const bf16_t* b0Src = Wo + (size_t)(bn * 128 + (w * 2 + 0) * 8 + srow) * DIM_ + scol;
    const bf16_t* b1Src = Wo + (size_t)(bn * 128 + (w * 2 + 1) * 8 + srow) * DIM_ + scol;

    f32x4 acc[2][2];
    #pragma unroll
    for (int i = 0; i < 2; i++)
        #pragma unroll
        for (int j = 0; j < 2; j++)
            acc[i][j] = (f32x4){0.f, 0.f, 0.f, 0.f};

    #define OSTAGE(buf, kb)                                          \
        {                                                            \
            gld16(aSrc + (kb), &As[buf][w * 512]);                   \
            gld16(b0Src + (kb), &Bs[buf][(w * 2 + 0) * 512]);        \
            gld16(b1Src + (kb), &Bs[buf][(w * 2 + 1) * 512]);        \
        }

    OSTAGE(0, 0);
    __syncthreads();

    for (int t = 0; t < 16; t++) {
        const int cur = t & 1;
        if (t < 15) OSTAGE(cur ^ 1, (t + 1) * 64);

        #pragma unroll
        for (int kk = 0; kk < 2; kk++) {
            const int swc = ((kk * 4 + g) ^ sw) * 8;
            bf16x8 af[2], bf[2];
            #pragma unroll
            for (int i = 0; i < 2; i++)
                af[i] = *(const bf16x8*)&As[cur][(wr * 32 + i * 16 + l15) * 64 + swc];
            #pragma unroll
            for (int j = 0; j < 2; j++)
                bf[j] = *(const bf16x8*)&Bs[cur][(wc * 32 + j * 16 + l15) * 64 + swc];
            #pragma unroll
            for (int i = 0; i < 2; i++)
                #pragma unroll
                for (int j = 0; j < 2; j++)
                    acc[i][j] = __builtin_amdgcn_mfma_f32_16x16x32_bf16(af[i], bf[j], acc[i][j], 0, 0, 0);
        }

        __syncthreads();
    }
    #undef OSTAGE

    const int r4 = g * 4;
    #pragma unroll
    for (int j = 0; j < 2; j++) {
        const int gc = bn * 128 + wc * 32 + j * 16 + l15;
        const float bv = bo[gc];
        #pragma unroll
        for (int i = 0; i < 2; i++) {
            #pragma unroll
            for (int r = 0; r < 4; r++) {
                const size_t gr = (size_t)(bm * 64 + wr * 32 + i * 16 + r4 + r) * DIM_ + gc;
                C[gr] = acc[i][j][r] + bv;
            }
        }
    }
}

// ---------------------------------------------------------------------------
// MFMA attention v9 (verified round 13/15/19, 43us): S^T via 32x32 MFMA,
// in-register P hand-off (cvt_pk + permlane32_swap), hw exp2, scalar L.
// ---------------------------------------------------------------------------
__device__ __forceinline__ u32 cvtpk_bf16(float lo, float hi) {
    u32 d;
    asm volatile("v_cvt_pk_bf16_f32 %0, %1, %2" : "=v"(d) : "v"(lo), "v"(hi));
    return d;
}

__global__ __launch_bounds__(512, 4) void attn_mfma9(
    const bf16_t* __restrict__ Qa,   // kb (attention-query rows n)
    const bf16_t* __restrict__ Ka,   // qb (attention-key rows m, pre-scaled by EXPC_)
    const bf16_t* __restrict__ Vtg,  // V^T per head [bh][d][m]
    bf16_t* __restrict__ O)
{
    __shared__ __align__(16) bf16_t Kt[2][128 * 72];   // 36.9 KB
    __shared__ __align__(16) bf16_t Vt[2][64 * 136];   // 34.8 KB

    const int tid  = threadIdx.x;
    const int lane = tid & 63;
    const int w    = tid >> 6;       // 0..7
    const int l31  = lane & 31;
    const int h5   = lane >> 5;

    const int nw = (w & 3) * 32;
    const int mo = (w >> 2) * 64;

    const int wg = blockIdx.x;
    const int id = (wg & 7) * 64 + (wg >> 3);
    const int bh = id >> 4;
    const int nt = id & 15;
    const int b  = bh >> 4, h = bh & 15;
    const int n0 = nt * 128;

    const size_t base = (size_t)b * NN_ * DIM_ + h * HD_;

    const bf16_t* qrow = Qa + base + (size_t)(n0 + nw + l31) * DIM_ + h5 * 8;
    bf16x8 qf[4];
    #pragma unroll
    for (int ks = 0; ks < 4; ks++)
        qf[ks] = *(const bf16x8*)(qrow + ks * 16);

    f32x16 oa0 = {}, oa1 = {};
    float Lp = 0.f;

    const bf16_t* vrow   = Vtg + (size_t)bh * HD_ * NN_;
    const bf16_t* kgbase = Ka + base;

    const int kr2 = tid >> 3;
    const int kc2 = (tid & 7) * 8;
    const int vc2 = (tid & 7) * 16;

    bf16x8 kA0, kB0, vA0, vA1;

    #define ISSUE(m0)                                                                        \
        {                                                                                    \
            kA0 = *(const bf16x8*)(kgbase + (size_t)((m0) + kr2) * DIM_ + kc2);              \
            kB0 = *(const bf16x8*)(kgbase + (size_t)((m0) + 64 + kr2) * DIM_ + kc2);         \
            const bf16x8* vp = (const bf16x8*)(vrow + (size_t)kr2 * NN_ + (m0) + vc2);       \
            vA0 = vp[0]; vA1 = vp[1];                                                        \
        }
    #define COMMIT(buf)                                                                      \
        {                                                                                    \
            *(bf16x8*)(Kt[buf] + kr2 * 72 + kc2)        = kA0;                               \
            *(bf16x8*)(Kt[buf] + (64 + kr2) * 72 + kc2) = kB0;                               \
            bf16_t* vd = Vt[buf] + kr2 * 136 + vc2;                                          \
            *(bf16x8*)(vd)     = vA0;                                                        \
            *(bf16x8*)(vd + 8) = vA1;                                                        \
        }

    ISSUE(0);
    COMMIT(0);
    __syncthreads();

    for (int mt = 0; mt < NN_ / 128; mt++) {
        const int cur = mt & 1;
        if (mt < NN_ / 128 - 1) ISSUE((mt + 1) * 128);

        const bf16_t* KtC = Kt[cur];
        const bf16_t* VtC = Vt[cur];

        f32x16 sa0 = {}, sa1 = {};
        __builtin_amdgcn_s_setprio(1);
        #pragma unroll
        for (int ks = 0; ks < 4; ks++) {
            bf16x8 kf0 = *(const bf16x8*)&KtC[(mo + l31) * 72 + ks * 16 + h5 * 8];
            bf16x8 kf1 = *(const bf16x8*)&KtC[(mo + 32 + l31) * 72 + ks * 16 + h5 * 8];
            sa0 = __builtin_amdgcn_mfma_f32_32x32x16_bf16(kf0, qf[ks], sa0, 0, 0, 0);
            sa1 = __builtin_amdgcn_mfma_f32_32x32x16_bf16(kf1, qf[ks], sa1, 0, 0, 0);
        }
        __builtin_amdgcn_s_setprio(0);

        // P = exp2(S^T) via hw v_exp_f32; scalar per-lane L (all p same n)
        float p0[16], p1[16];
        #pragma unroll
        for (int r = 0; r < 16; r++) { p0[r] = exp2_hw(sa0[r]); p1[r] = exp2_hw(sa1[r]); }
        {
            float s0 = (p0[0] + p0[1]) + (p0[2] + p0[3]);
            float s1 = (p0[4] + p0[5]) + (p0[6] + p0[7]);
            float s2 = (p0[8] + p0[9]) + (p0[10] + p0[11]);
            float s3 = (p0[12] + p0[13]) + (p0[14] + p0[15]);
            float t0 = (p1[0] + p1[1]) + (p1[2] + p1[3]);
            float t1 = (p1[4] + p1[5]) + (p1[6] + p1[7]);
            float t2 = (p1[8] + p1[9]) + (p1[10] + p1[11]);
            float t3 = (p1[12] + p1[13]) + (p1[14] + p1[15]);
            Lp += ((s0 + s1) + (s2 + s3)) + ((t0 + t1) + (t2 + t3));
        }

        bf16x8 pf[4];
        #pragma unroll
        for (int mb = 0; mb < 4; mb++) {
            const float* pp = (mb & 2) ? p1 : p0;
            const int rb = (mb & 1) * 8;
            u32 x0 = cvtpk_bf16(pp[rb + 0], pp[rb + 1]);
            u32 x1 = cvtpk_bf16(pp[rb + 2], pp[rb + 3]);
            u32 y0 = cvtpk_bf16(pp[rb + 4], pp[rb + 5]);
            u32 y1 = cvtpk_bf16(pp[rb + 6], pp[rb + 7]);
            asm volatile("v_permlane32_swap_b32 %0, %1" : "+v"(x0), "+v"(y0));
            asm volatile("v_permlane32_swap_b32 %0, %1" : "+v"(x1), "+v"(y1));
            u32x4 t; t.x = x0; t.y = x1; t.z = y0; t.w = y1;
            pf[mb] = __builtin_bit_cast(bf16x8, t);
        }

        __builtin_amdgcn_s_setprio(1);
        #pragma unroll
        for (int ms = 0; ms < 4; ms++) {
            bf16x8 vf0 = *(const bf16x8*)&VtC[l31 * 136 + mo + ms * 16 + h5 * 8];
            bf16x8 vf1 = *(const bf16x8*)&VtC[(32 + l31) * 136 + mo + ms * 16 + h5 * 8];
            oa0 = __builtin_amdgcn_mfma_f32_32x32x16_bf16(pf[ms], vf0, oa0, 0, 0, 0);
            oa1 = __builtin_amdgcn_mfma_f32_32x32x16_bf16(pf[ms], vf1, oa1, 0, 0, 0);
        }
        __builtin_amdgcn_s_setprio(0);

        if (mt < NN_ / 128 - 1) COMMIT(cur ^ 1);
        __syncthreads();
    }
    #undef ISSUE
    #undef COMMIT

    Lp += __shfl_xor(Lp, 32);

    float* scratch0 = (float*)Kt;
    float* scratch1 = (float*)Vt;
    if (w >= 4) {
        float* buf = (w < 6) ? (scratch0 + (w - 4) * 2112)
                             : (scratch1 + (w - 6) * 2112);
        #pragma unroll
        for (int reg = 0; reg < 16; reg++) {
            buf[reg * 64 + lane]        = oa0[reg];
            buf[1024 + reg * 64 + lane] = oa1[reg];
        }
        buf[2048 + lane] = Lp;
    }
    __syncthreads();
    if (w < 4) {
        const float* buf = (w < 2) ? (scratch0 + w * 2112)
                                   : (scratch1 + (w - 2) * 2112);
        #pragma unroll
        for (int reg = 0; reg < 16; reg++) {
            oa0[reg] += buf[reg * 64 + lane];
            oa1[reg] += buf[1024 + reg * 64 + lane];
        }
        Lp += buf[2048 + lane];
    }
    __syncthreads();

    float* Lsh = scratch0 + 4224;
    if (w < 4) Lsh[nw + l31] = Lp;
    __syncthreads();

    if (w < 4) {
        #pragma unroll
        for (int reg = 0; reg < 16; reg++) {
            const int nr = (reg & 3) + 8 * (reg >> 2) + 4 * h5;
            const float il = 1.f / Lsh[nw + nr];
            const size_t rowoff = base + (size_t)(n0 + nw + nr) * DIM_;
            O[rowoff + l31]      = (bf16_t)(oa0[reg] * il);
            O[rowoff + 32 + l31] = (bf16_t)(oa1[reg] * il);
        }
    }
}

// ---------------------------------------------------------------------------
extern "C" void kernel_launch(void* const* d_in, const int* in_sizes, int n_in,
                              void* d_out, int out_size, void* d_ws, size_t ws_size,
                              hipStream_t stream)
{
    const float* x  = (const float*)d_in[0];
    const float* Wq = (const float*)d_in[1];
    const float* bq = (const float*)d_in[2];
    const float* Wk = (const float*)d_in[3];
    const float* bk = (const float*)d_in[4];
    const float* Wv = (const float*)d_in[5];
    const float* bv = (const float*)d_in[6];
    const float* Wo = (const float*)d_in[7];
    const float* bo = (const float*)d_in[8];
    float* out = (float*)d_out;

    const size_t SEG = (size_t)MTOT * DIM_;   // 4M elems = 8MB bf16
    bf16_t* xb = (bf16_t*)d_ws;
    bf16_t* qb = xb + SEG;
    bf16_t* kb = qb + SEG;
    bf16_t* vt = kb + SEG;   // V^T written directly by gemm_qkv
    bf16_t* ab = xb;         // xb dead after QKV gemm

    // bf16 weights in [32MB, 40MB)
    bf16_t* wqb = vt + SEG;
    bf16_t* wkb = wqb + (size_t)DIM_ * DIM_;
    bf16_t* wvb = wkb + (size_t)DIM_ * DIM_;
    bf16_t* wob = wvb + (size_t)DIM_ * DIM_;

    cvt_all<<<dim3(4096), 256, 0, stream>>>(x, Wq, Wk, Wv, Wo, xb, wqb, wkb, wvb, wob);

    gemm_qkv<<<dim3(16, 32), 512, 0, stream>>>(
        xb, wqb, wkb, wvb, bq, bk, bv, qb, kb, vt);

    attn_mfma9<<<dim3(512), 512, 0, stream>>>(kb, qb, vt, ab);

    gemm_o<<<dim3(8, 64), 512, 0, stream>>>(ab, wob, bo, out);
}

// Round 23
// 101.718 us; speedup vs baseline: 1.0810x; 1.0024x over previous
//
#include <hip/hip_runtime.h>
#include <hip/hip_bf16.h>
#include <cstdint>
#include <cstddef>

typedef __bf16 bf16_t;
typedef __bf16 bf16x4 __attribute__((ext_vector_type(4)));
typedef __bf16 bf16x8 __attribute__((ext_vector_type(8)));
typedef float  f32x4  __attribute__((ext_vector_type(4)));
typedef float  f32x16 __attribute__((ext_vector_type(16)));
typedef unsigned int u32;
typedef unsigned int u32x4 __attribute__((ext_vector_type(4)));

#define DIM_   1024
#define HEADS_ 16
#define HD_    64
#define BB_    2
#define NN_    2048
#define MTOT   (BB_*NN_)
static constexpr float SCALE_ = 0.03125f;              // 1/sqrt(1024)
static constexpr float EXPC_  = 0.045084220027780106f; // SCALE * log2(e), folded into q-proj

__device__ __forceinline__ float exp2_hw(float x) {
    float r;
    asm("v_exp_f32 %0, %1" : "=v"(r) : "v"(x));
    return r;
}

// ---------------------------------------------------------------------------
// fp32 -> bf16 bulk convert, all 5 arrays in one launch.
// ---------------------------------------------------------------------------
__global__ __launch_bounds__(256) void cvt_all(
    const float* __restrict__ X,
    const float* __restrict__ W0, const float* __restrict__ W1,
    const float* __restrict__ W2, const float* __restrict__ W3,
    bf16_t* __restrict__ xo,
    bf16_t* __restrict__ o0, bf16_t* __restrict__ o1,
    bf16_t* __restrict__ o2, bf16_t* __restrict__ o3)
{
    const int bid = blockIdx.x;
    const float* src;
    bf16_t* dst;
    int lb;
    if (bid < 2048) { src = X; dst = xo; lb = bid; }
    else {
        const int w = (bid - 2048) >> 9;
        lb = (bid - 2048) & 511;
        src = (w == 0) ? W0 : (w == 1) ? W1 : (w == 2) ? W2 : W3;
        dst = (w == 0) ? o0 : (w == 1) ? o1 : (w == 2) ? o2 : o3;
    }
    const size_t i = ((size_t)lb * 256 + threadIdx.x) * 8;
    f32x4 a = *(const f32x4*)(src + i);
    f32x4 b = *(const f32x4*)(src + i + 4);
    bf16x8 o;
    o[0] = (bf16_t)a.x; o[1] = (bf16_t)a.y; o[2] = (bf16_t)a.z; o[3] = (bf16_t)a.w;
    o[4] = (bf16_t)b.x; o[5] = (bf16_t)b.y; o[6] = (bf16_t)b.z; o[7] = (bf16_t)b.w;
    *(bf16x8*)(dst + i) = o;
}

// ---------------------------------------------------------------------------
__device__ __forceinline__ void gld16(const bf16_t* g, bf16_t* l) {
    __builtin_amdgcn_global_load_lds(
        (const __attribute__((address_space(1))) unsigned int*)g,
        (__attribute__((address_space(3))) unsigned int*)l, 16, 0, 0);
}

// ---------------------------------------------------------------------------
// Fused QKV GEMM, BK=64 dbuf, fused per-head V^T output, T2 XOR-swizzled LDS.
// (verified round 15/19)
// ---------------------------------------------------------------------------
__global__ __launch_bounds__(512) void gemm_qkv(
    const bf16_t* __restrict__ A,
    const bf16_t* __restrict__ Wq, const bf16_t* __restrict__ Wk, const bf16_t* __restrict__ Wv,
    const float* __restrict__ bq, const float* __restrict__ bk, const float* __restrict__ bv,
    bf16_t* __restrict__ Cq, bf16_t* __restrict__ Ck, bf16_t* __restrict__ Vt)
{
    __shared__ __align__(16) bf16_t As[2][128 * 64];      // 32KB
    __shared__ __align__(16) bf16_t Bs[2][3 * 64 * 64];   // 48KB

    const int tid  = threadIdx.x;
    const int lane = tid & 63;
    const int w    = tid >> 6;        // 0..7
    const int wr   = w >> 1;          // 0..3: 32-row strip
    const int wc   = w & 1;           // 0..1: 32-col half
    const int bn   = blockIdx.x;      // 0..15 == head h
    const int bm   = blockIdx.y;      // 0..31

    const int l15 = lane & 15;
    const int g   = lane >> 4;
    const int sw  = l15 & 7;           // read-side row XOR key

    const int srow = lane >> 3;                          // 0..7 within chunk
    const int scol = ((lane & 7) ^ srow) * 8;            // pre-swizzled source col

    const bf16_t* aSrc0 = A  + (size_t)(bm * 128 + (w * 2 + 0) * 8 + srow) * DIM_ + scol;
    const bf16_t* aSrc1 = A  + (size_t)(bm * 128 + (w * 2 + 1) * 8 + srow) * DIM_ + scol;
    const bf16_t* qSrc  = Wq + (size_t)(bn * 64 + w * 8 + srow) * DIM_ + scol;
    const bf16_t* kSrc  = Wk + (size_t)(bn * 64 + w * 8 + srow) * DIM_ + scol;
    const bf16_t* vSrc  = Wv + (size_t)(bn * 64 + w * 8 + srow) * DIM_ + scol;

    f32x4 aq[2][2], ak[2][2], av[2][2];
    #pragma unroll
    for (int i = 0; i < 2; i++)
        #pragma unroll
        for (int j = 0; j < 2; j++) {
            aq[i][j] = (f32x4){0.f, 0.f, 0.f, 0.f};
            ak[i][j] = (f32x4){0.f, 0.f, 0.f, 0.f};
            av[i][j] = (f32x4){0.f, 0.f, 0.f, 0.f};
        }

    #define QSTAGE(buf, kb)                                       \
        {                                                         \
            gld16(aSrc0 + (kb), &As[buf][(w * 2 + 0) * 512]);     \
            gld16(aSrc1 + (kb), &As[buf][(w * 2 + 1) * 512]);     \
            gld16(qSrc + (kb), &Bs[buf][w * 512]);                \
            gld16(kSrc + (kb), &Bs[buf][4096 + w * 512]);         \
            gld16(vSrc + (kb), &Bs[buf][8192 + w * 512]);         \
        }

    QSTAGE(0, 0);
    __syncthreads();

    for (int t = 0; t < 16; t++) {
        const int cur = t & 1;
        if (t < 15) QSTAGE(cur ^ 1, (t + 1) * 64);

        #pragma unroll
        for (int kk = 0; kk < 2; kk++) {
            const int swc = ((kk * 4 + g) ^ sw) * 8;   // swizzled col offset
            bf16x8 af[2];
            #pragma unroll
            for (int i = 0; i < 2; i++)
                af[i] = *(const bf16x8*)&As[cur][(wr * 32 + i * 16 + l15) * 64 + swc];
            bf16x8 bqf[2], bkf[2], bvf[2];
            #pragma unroll
            for (int j = 0; j < 2; j++) {
                const int off = (wc * 32 + j * 16 + l15) * 64 + swc;
                bqf[j] = *(const bf16x8*)&Bs[cur][off];
                bkf[j] = *(const bf16x8*)&Bs[cur][4096 + off];
                bvf[j] = *(const bf16x8*)&Bs[cur][8192 + off];
            }
            #pragma unroll
            for (int i = 0; i < 2; i++)
                #pragma unroll
                for (int j = 0; j < 2; j++) {
                    aq[i][j] = __builtin_amdgcn_mfma_f32_16x16x32_bf16(af[i], bqf[j], aq[i][j], 0, 0, 0);
                    ak[i][j] = __builtin_amdgcn_mfma_f32_16x16x32_bf16(af[i], bkf[j], ak[i][j], 0, 0, 0);
                    av[i][j] = __builtin_amdgcn_mfma_f32_16x16x32_bf16(af[i], bvf[j], av[i][j], 0, 0, 0);
                }
        }

        __syncthreads();
    }
    #undef QSTAGE

    // epilogue: q,k direct; v -> LDS transpose -> coalesced V^T write
    bf16_t* Ts = (bf16_t*)As;
    const int r4 = g * 4;
    #pragma unroll
    for (int j = 0; j < 2; j++) {
        const int lc = wc * 32 + j * 16 + l15;
        const int gc = bn * 64 + lc;
        const float vq = bq[gc], vk = bk[gc], vv = bv[gc];
        #pragma unroll
        for (int i = 0; i < 2; i++) {
            #pragma unroll
            for (int r = 0; r < 4; r++) {
                const int lm = wr * 32 + i * 16 + r4 + r;
                const size_t gr = (size_t)(bm * 128 + lm) * DIM_ + gc;
                Cq[gr] = (bf16_t)((aq[i][j][r] + vq) * EXPC_);
                Ck[gr] = (bf16_t)(ak[i][j][r] + vk);
                Ts[lc * 136 + lm] = (bf16_t)(av[i][j][r] + vv);
            }
        }
    }
    __syncthreads();
    {
        const int b  = bm >> 4;
        const int m0 = (bm & 15) * 128;
        const int d  = tid >> 3;
        const int c  = (tid & 7) * 16;
        bf16x8 v0 = *(const bf16x8*)&Ts[d * 136 + c];
        bf16x8 v1 = *(const bf16x8*)&Ts[d * 136 + c + 8];
        bf16_t* dst = Vt + ((size_t)(b * HEADS_ + bn) * HD_ + d) * NN_ + m0 + c;
        *(bf16x8*)dst       = v0;
        *(bf16x8*)(dst + 8) = v1;
    }
}

// ---------------------------------------------------------------------------
// O-proj GEMM, 2-phase dbuf + T2 XOR-swizzled LDS (verified round 15/19).
// ---------------------------------------------------------------------------
__global__ __launch_bounds__(512) void gemm_o(
    const bf16_t* __restrict__ A, const bf16_t* __restrict__ Wo,
    const float* __restrict__ bo, float* __restrict__ C)
{
    __shared__ __align__(16) bf16_t As[2][64 * 64];
    __shared__ __align__(16) bf16_t Bs[2][128 * 64];

    const int tid  = threadIdx.x;
    const int lane = tid & 63;
    const int w    = tid >> 6;
    const int wr   = w & 1;
    const int wc   = w >> 1;
    const int bn   = blockIdx.x;
    const int bm   = blockIdx.y;

    const int l15 = lane & 15;
    const int g   = lane >> 4;
    const int sw  = l15 & 7;

    const int srow = lane >> 3;
    const int scol = ((lane & 7) ^ srow) * 8;

    const bf16_t* aSrc  = A  + (size_t)(bm * 64 + w * 8 + srow) * DIM_ + scol;
    const bf16_t* b0Src = Wo + (size_t)(bn * 128 + (w * 2 + 0) * 8 + srow) * DIM_ + scol;
    const bf16_t* b1Src = Wo + (size_t)(bn * 128 + (w * 2 + 1) * 8 + srow) * DIM_ + scol;

    f32x4 acc[2][2];
    #pragma unroll
    for (int i = 0; i < 2; i++)
        #pragma unroll
        for (int j = 0; j < 2; j++)
            acc[i][j] = (f32x4){0.f, 0.f, 0.f, 0.f};

    #define OSTAGE(buf, kb)                                          \
        {                                                            \
            gld16(aSrc + (kb), &As[buf][w * 512]);                   \
            gld16(b0Src + (kb), &Bs[buf][(w * 2 + 0) * 512]);        \
            gld16(b1Src + (kb), &Bs[buf][(w * 2 + 1) * 512]);        \
        }

    OSTAGE(0, 0);
    __syncthreads();

    for (int t = 0; t < 16; t++) {
        const int cur = t & 1;
        if (t < 15) OSTAGE(cur ^ 1, (t + 1) * 64);

        #pragma unroll
        for (int kk = 0; kk < 2; kk++) {
            const int swc = ((kk * 4 + g) ^ sw) * 8;
            bf16x8 af[2], bf[2];
            #pragma unroll
            for (int i = 0; i < 2; i++)
                af[i] = *(const bf16x8*)&As[cur][(wr * 32 + i * 16 + l15) * 64 + swc];
            #pragma unroll
            for (int j = 0; j < 2; j++)
                bf[j] = *(const bf16x8*)&Bs[cur][(wc * 32 + j * 16 + l15) * 64 + swc];
            #pragma unroll
            for (int i = 0; i < 2; i++)
                #pragma unroll
                for (int j = 0; j < 2; j++)
                    acc[i][j] = __builtin_amdgcn_mfma_f32_16x16x32_bf16(af[i], bf[j], acc[i][j], 0, 0, 0);
        }

        __syncthreads();
    }
    #undef OSTAGE

    const int r4 = g * 4;
    #pragma unroll
    for (int j = 0; j < 2; j++) {
        const int gc = bn * 128 + wc * 32 + j * 16 + l15;
        const float bv = bo[gc];
        #pragma unroll
        for (int i = 0; i < 2; i++) {
            #pragma unroll
            for (int r = 0; r < 4; r++) {
                const size_t gr = (size_t)(bm * 64 + wr * 32 + i * 16 + r4 + r) * DIM_ + gc;
                C[gr] = acc[i][j][r] + bv;
            }
        }
    }
}

// ---------------------------------------------------------------------------
// MFMA attention v9 (verified round 13/15/19, 43us): S^T via 32x32 MFMA,
// in-register P hand-off (cvt_pk + permlane32_swap), hw exp2, scalar L.
// ---------------------------------------------------------------------------
__device__ __forceinline__ u32 cvtpk_bf16(float lo, float hi) {
    u32 d;
    asm volatile("v_cvt_pk_bf16_f32 %0, %1, %2" : "=v"(d) : "v"(lo), "v"(hi));
    return d;
}

__global__ __launch_bounds__(512, 4) void attn_mfma9(
    const bf16_t* __restrict__ Qa,   // kb (attention-query rows n)
    const bf16_t* __restrict__ Ka,   // qb (attention-key rows m, pre-scaled by EXPC_)
    const bf16_t* __restrict__ Vtg,  // V^T per head [bh][d][m]
    bf16_t* __restrict__ O)
{
    __shared__ __align__(16) bf16_t Kt[2][128 * 72];   // 36.9 KB
    __shared__ __align__(16) bf16_t Vt[2][64 * 136];   // 34.8 KB

    const int tid  = threadIdx.x;
    const int lane = tid & 63;
    const int w    = tid >> 6;       // 0..7
    const int l31  = lane & 31;
    const int h5   = lane >> 5;

    const int nw = (w & 3) * 32;
    const int mo = (w >> 2) * 64;

    const int wg = blockIdx.x;
    const int id = (wg & 7) * 64 + (wg >> 3);
    const int bh = id >> 4;
    const int nt = id & 15;
    const int b  = bh >> 4, h = bh & 15;
    const int n0 = nt * 128;

    const size_t base = (size_t)b * NN_ * DIM_ + h * HD_;

    const bf16_t* qrow = Qa + base + (size_t)(n0 + nw + l31) * DIM_ + h5 * 8;
    bf16x8 qf[4];
    #pragma unroll
    for (int ks = 0; ks < 4; ks++)
        qf[ks] = *(const bf16x8*)(qrow + ks * 16);

    f32x16 oa0 = {}, oa1 = {};
    float Lp = 0.f;

    const bf16_t* vrow   = Vtg + (size_t)bh * HD_ * NN_;
    const bf16_t* kgbase = Ka + base;

    const int kr2 = tid >> 3;
    const int kc2 = (tid & 7) * 8;
    const int vc2 = (tid & 7) * 16;

    bf16x8 kA0, kB0, vA0, vA1;

    #define ISSUE(m0)                                                                        \
        {                                                                                    \
            kA0 = *(const bf16x8*)(kgbase + (size_t)((m0) + kr2) * DIM_ + kc2);              \
            kB0 = *(const bf16x8*)(kgbase + (size_t)((m0) + 64 + kr2) * DIM_ + kc2);         \
            const bf16x8* vp = (const bf16x8*)(vrow + (size_t)kr2 * NN_ + (m0) + vc2);       \
            vA0 = vp[0]; vA1 = vp[1];                                                        \
        }
    #define COMMIT(buf)                                                                      \
        {                                                                                    \
            *(bf16x8*)(Kt[buf] + kr2 * 72 + kc2)        = kA0;                               \
            *(bf16x8*)(Kt[buf] + (64 + kr2) * 72 + kc2) = kB0;                               \
            bf16_t* vd = Vt[buf] + kr2 * 136 + vc2;                                          \
            *(bf16x8*)(vd)     = vA0;                                                        \
            *(bf16x8*)(vd + 8) = vA1;                                                        \
        }

    ISSUE(0);
    COMMIT(0);
    __syncthreads();

    for (int mt = 0; mt < NN_ / 128; mt++) {
        const int cur = mt & 1;
        if (mt < NN_ / 128 - 1) ISSUE((mt + 1) * 128);

        const bf16_t* KtC = Kt[cur];
        const bf16_t* VtC = Vt[cur];

        f32x16 sa0 = {}, sa1 = {};
        __builtin_amdgcn_s_setprio(1);
        #pragma unroll
        for (int ks = 0; ks < 4; ks++) {
            bf16x8 kf0 = *(const bf16x8*)&KtC[(mo + l31) * 72 + ks * 16 + h5 * 8];
            bf16x8 kf1 = *(const bf16x8*)&KtC[(mo + 32 + l31) * 72 + ks * 16 + h5 * 8];
            sa0 = __builtin_amdgcn_mfma_f32_32x32x16_bf16(kf0, qf[ks], sa0, 0, 0, 0);
            sa1 = __builtin_amdgcn_mfma_f32_32x32x16_bf16(kf1, qf[ks], sa1, 0, 0, 0);
        }
        __builtin_amdgcn_s_setprio(0);

        // P = exp2(S^T) via hw v_exp_f32; scalar per-lane L (all p same n)
        float p0[16], p1[16];
        #pragma unroll
        for (int r = 0; r < 16; r++) { p0[r] = exp2_hw(sa0[r]); p1[r] = exp2_hw(sa1[r]); }
        {
            float s0 = (p0[0] + p0[1]) + (p0[2] + p0[3]);
            float s1 = (p0[4] + p0[5]) + (p0[6] + p0[7]);
            float s2 = (p0[8] + p0[9]) + (p0[10] + p0[11]);
            float s3 = (p0[12] + p0[13]) + (p0[14] + p0[15]);
            float t0 = (p1[0] + p1[1]) + (p1[2] + p1[3]);
            float t1 = (p1[4] + p1[5]) + (p1[6] + p1[7]);
            float t2 = (p1[8] + p1[9]) + (p1[10] + p1[11]);
            float t3 = (p1[12] + p1[13]) + (p1[14] + p1[15]);
            Lp += ((s0 + s1) + (s2 + s3)) + ((t0 + t1) + (t2 + t3));
        }

        bf16x8 pf[4];
        #pragma unroll
        for (int mb = 0; mb < 4; mb++) {
            const float* pp = (mb & 2) ? p1 : p0;
            const int rb = (mb & 1) * 8;
            u32 x0 = cvtpk_bf16(pp[rb + 0], pp[rb + 1]);
            u32 x1 = cvtpk_bf16(pp[rb + 2], pp[rb + 3]);
            u32 y0 = cvtpk_bf16(pp[rb + 4], pp[rb + 5]);
            u32 y1 = cvtpk_bf16(pp[rb + 6], pp[rb + 7]);
            asm volatile("v_permlane32_swap_b32 %0, %1" : "+v"(x0), "+v"(y0));
            asm volatile("v_permlane32_swap_b32 %0, %1" : "+v"(x1), "+v"(y1));
            u32x4 t; t.x = x0; t.y = x1; t.z = y0; t.w = y1;
            pf[mb] = __builtin_bit_cast(bf16x8, t);
        }

        __builtin_amdgcn_s_setprio(1);
        #pragma unroll
        for (int ms = 0; ms < 4; ms++) {
            bf16x8 vf0 = *(const bf16x8*)&VtC[l31 * 136 + mo + ms * 16 + h5 * 8];
            bf16x8 vf1 = *(const bf16x8*)&VtC[(32 + l31) * 136 + mo + ms * 16 + h5 * 8];
            oa0 = __builtin_amdgcn_mfma_f32_32x32x16_bf16(pf[ms], vf0, oa0, 0, 0, 0);
            oa1 = __builtin_amdgcn_mfma_f32_32x32x16_bf16(pf[ms], vf1, oa1, 0, 0, 0);
        }
        __builtin_amdgcn_s_setprio(0);

        if (mt < NN_ / 128 - 1) COMMIT(cur ^ 1);
        __syncthreads();
    }
    #undef ISSUE
    #undef COMMIT

    Lp += __shfl_xor(Lp, 32);

    float* scratch0 = (float*)Kt;
    float* scratch1 = (float*)Vt;
    if (w >= 4) {
        float* buf = (w < 6) ? (scratch0 + (w - 4) * 2112)
                             : (scratch1 + (w - 6) * 2112);
        #pragma unroll
        for (int reg = 0; reg < 16; reg++) {
            buf[reg * 64 + lane]        = oa0[reg];
            buf[1024 + reg * 64 + lane] = oa1[reg];
        }
        buf[2048 + lane] = Lp;
    }
    __syncthreads();
    if (w < 4) {
        const float* buf = (w < 2) ? (scratch0 + w * 2112)
                                   : (scratch1 + (w - 2) * 2112);
        #pragma unroll
        for (int reg = 0; reg < 16; reg++) {
            oa0[reg] += buf[reg * 64 + lane];
            oa1[reg] += buf[1024 + reg * 64 + lane];
        }
        Lp += buf[2048 + lane];
    }
    __syncthreads();

    float* Lsh = scratch0 + 4224;
    if (w < 4) Lsh[nw + l31] = Lp;
    __syncthreads();

    if (w < 4) {
        #pragma unroll
        for (int reg = 0; reg < 16; reg++) {
            const int nr = (reg & 3) + 8 * (reg >> 2) + 4 * h5;
            const float il = 1.f / Lsh[nw + nr];
            const size_t rowoff = base + (size_t)(n0 + nw + nr) * DIM_;
            O[rowoff + l31]      = (bf16_t)(oa0[reg] * il);
            O[rowoff + 32 + l31] = (bf16_t)(oa1[reg] * il);
        }
    }
}

// ---------------------------------------------------------------------------
extern "C" void kernel_launch(void* const* d_in, const int* in_sizes, int n_in,
                              void* d_out, int out_size, void* d_ws, size_t ws_size,
                              hipStream_t stream)
{
    const float* x  = (const float*)d_in[0];
    const float* Wq = (const float*)d_in[1];
    const float* bq = (const float*)d_in[2];
    const float* Wk = (const float*)d_in[3];
    const float* bk = (const float*)d_in[4];
    const float* Wv = (const float*)d_in[5];
    const float* bv = (const float*)d_in[6];
    const float* Wo = (const float*)d_in[7];
    const float* bo = (const float*)d_in[8];
    float* out = (float*)d_out;

    const size_t SEG = (size_t)MTOT * DIM_;   // 4M elems = 8MB bf16
    bf16_t* xb = (bf16_t*)d_ws;
    bf16_t* qb = xb + SEG;
    bf16_t* kb = qb + SEG;
    bf16_t* vt = kb + SEG;   // V^T written directly by gemm_qkv
    bf16_t* ab = xb;         // xb dead after QKV gemm

    // bf16 weights in [32MB, 40MB)
    bf16_t* wqb = vt + SEG;
    bf16_t* wkb = wqb + (size_t)DIM_ * DIM_;
    bf16_t* wvb = wkb + (size_t)DIM_ * DIM_;
    bf16_t* wob = wvb + (size_t)DIM_ * DIM_;

    cvt_all<<<dim3(4096), 256, 0, stream>>>(x, Wq, Wk, Wv, Wo, xb, wqb, wkb, wvb, wob);

    gemm_qkv<<<dim3(16, 32), 512, 0, stream>>>(
        xb, wqb, wkb, wvb, bq, bk, bv, qb, kb, vt);

    attn_mfma9<<<dim3(512), 512, 0, stream>>>(kb, qb, vt, ab);

    gemm_o<<<dim3(8, 64), 512, 0, stream>>>(ab, wob, bo, out);
}